// Round 1
// baseline (2703.174 us; speedup 1.0000x reference)
//
#include <hip/hip_runtime.h>
#include <hip/hip_bf16.h>

#define B    16
#define NA   25200
#define NCH  85
#define NCLS 80
#define K    2048
#define CAP  8192
#define DET  300
#define SBASE  0x3FD0000000000000ULL   // bits of 0.25 (double)
#define SSHIFT 42                      // (1.0-0.25) bit-range 2^53 -> 2048 bins

typedef unsigned long long u64;
typedef unsigned int u32;

__device__ __forceinline__ double dsig(float x) {
    return 1.0 / (1.0 + exp(-(double)x));
}

// ---- Pass 1: per-image histogram of score bits (score > 0.25 only) ----
__global__ void k_hist(const float* __restrict__ head, int* __restrict__ hist) {
    int t = blockIdx.x * blockDim.x + threadIdx.x;
    if (t >= B * NA) return;
    int img = t / NA, a = t - img * NA;
    const float* row = head + ((size_t)img * NA + a) * NCH;
    double so = dsig(row[4]);
    int* h = hist + img * 2048;
    for (int c = 0; c < NCLS; ++c) {
        double s = dsig(row[5 + c]) * so;   // class * objectness
        if (s > 0.25) {
            u64 bits = (u64)__double_as_longlong(s);
            atomicAdd(&h[(int)((bits - SBASE) >> SSHIFT)], 1);
        }
    }
}

// ---- Pass 2: find cut bin so that >=2048 candidates survive ----
__global__ void k_cut(const int* __restrict__ hist, u64* __restrict__ cut) {
    int img = threadIdx.x;
    if (img >= B) return;
    const int* h = hist + img * 2048;
    int cum = 0; u64 cb = 0;   // cb==0 => take everything >0.25
    for (int b = 2047; b >= 0; --b) {
        cum += h[b];
        if (cum >= K) { cb = SBASE + ((u64)b << SSHIFT); break; }
    }
    cut[img] = cb;
}

// ---- Pass 3: collect candidates at/above the cut ----
__global__ void k_collect(const float* __restrict__ head, const u64* __restrict__ cut,
                          u32* __restrict__ cnt, u64* __restrict__ sb, u32* __restrict__ si) {
    int t = blockIdx.x * blockDim.x + threadIdx.x;
    if (t >= B * NA) return;
    int img = t / NA, a = t - img * NA;
    const float* row = head + ((size_t)img * NA + a) * NCH;
    double so = dsig(row[4]);
    u64 cutb = cut[img];
    u64* sbi = sb + (size_t)img * CAP;
    u32* sii = si + (size_t)img * CAP;
    for (int c = 0; c < NCLS; ++c) {
        double s = dsig(row[5 + c]) * so;
        if (s > 0.25) {
            u64 bits = (u64)__double_as_longlong(s);
            if (bits >= cutb) {
                u32 pos = atomicAdd(&cnt[img], 1u);
                if (pos < CAP) { sbi[pos] = bits; sii[pos] = (u32)(a * NCLS + c); }
            }
        }
    }
}

// ---- Pass 4: per-image exact bitonic sort (desc score-bits, asc index) ----
__global__ void k_sort(const u32* __restrict__ cntArr, u64* __restrict__ sb, u32* __restrict__ si) {
    int img = blockIdx.x;
    int tid = threadIdx.x;
    u64* A = sb + (size_t)img * CAP;
    u32* I = si + (size_t)img * CAP;
    int cnt = (int)cntArr[img]; if (cnt > CAP) cnt = CAP;
    int n = K; while (n < cnt) n <<= 1;                    // pow2 >= max(cnt, 2048)
    for (int t = cnt + tid; t < n; t += blockDim.x) { A[t] = 0ULL; I[t] = 0xFFFFFFFFu; }
    for (unsigned k = 2; k <= (unsigned)n; k <<= 1) {
        for (unsigned j = k >> 1; j > 0; j >>= 1) {
            __syncthreads();
            for (unsigned i = tid; i < (unsigned)n; i += blockDim.x) {
                unsigned l = i ^ j;
                if (l > i) {
                    u64 s1 = A[i], s2 = A[l];
                    u32 i1 = I[i], i2 = I[l];
                    bool before = (s1 > s2) || (s1 == s2 && i1 < i2); // i should precede l
                    bool up = ((i & k) == 0);
                    if (up != before) { A[i] = s2; A[l] = s1; I[i] = i2; I[l] = i1; }
                }
            }
        }
    }
}

// ---- Pass 5: decode boxes (f64), class-offset, greedy NMS, emit top-300 ----
__global__ void __launch_bounds__(256) k_nms(const float* __restrict__ head,
        const float* __restrict__ grid, const float* __restrict__ ag, const float* __restrict__ stv,
        const u64* __restrict__ sb, const u32* __restrict__ si,
        double* __restrict__ cbox, double* __restrict__ obox, double* __restrict__ area,
        float* __restrict__ out) {
    int img = blockIdx.x;
    int tid = threadIdx.x;
    const u64* sbi = sb + (size_t)img * CAP;
    const u32* sii = si + (size_t)img * CAP;
    double* cb = cbox + (size_t)img * K * 4;
    double* ob = obox + (size_t)img * K * 4;
    double* ar = area + (size_t)img * K;
    __shared__ char keep[K];
    __shared__ double red[256];

    double lmax = -1e300;
    for (int t = tid; t < K; t += 256) {
        u64 s = sbi[t];
        bool valid = (s != 0ULL);
        keep[t] = valid ? 1 : 0;
        double b0 = 0, b1 = 0, b2 = 0, b3 = 0;
        if (valid) {
            int a = (int)(sii[t] / NCLS);
            const float* row = head + ((size_t)img * NA + a) * NCH;
            double p0 = dsig(row[0]), p1 = dsig(row[1]), p2 = dsig(row[2]), p3 = dsig(row[3]);
            double st = (double)stv[a];
            double xc = (p0 * 2.0 - 0.5 + (double)grid[a * 2 + 0]) * st;
            double yc = (p1 * 2.0 - 0.5 + (double)grid[a * 2 + 1]) * st;
            double w = p2 * 2.0; w = (w * w) * (double)ag[a * 2 + 0];
            double h = p3 * 2.0; h = (h * h) * (double)ag[a * 2 + 1];
            b0 = xc - w * 0.5; b1 = yc - h * 0.5;
            b2 = xc + w * 0.5; b3 = yc + h * 0.5;
            lmax = fmax(lmax, fmax(fmax(b0, b1), fmax(b2, b3)));
        }
        cb[t * 4 + 0] = b0; cb[t * 4 + 1] = b1; cb[t * 4 + 2] = b2; cb[t * 4 + 3] = b3;
    }
    red[tid] = lmax;
    __syncthreads();
    for (int sft = 128; sft > 0; sft >>= 1) {
        if (tid < sft) red[tid] = fmax(red[tid], red[tid + sft]);
        __syncthreads();
    }
    double offb = red[0] + 1.0;   // (max(cand) + 1)

    for (int t = tid; t < K; t += 256) {
        double o0 = 0, o1 = 0, o2 = 0, o3 = 0, aa = 0;
        if (keep[t]) {
            int lab = (int)(sii[t] % NCLS);
            double off = offb * (double)lab;
            o0 = cb[t * 4 + 0] + off; o1 = cb[t * 4 + 1] + off;
            o2 = cb[t * 4 + 2] + off; o3 = cb[t * 4 + 3] + off;
            aa = (o2 - o0) * (o3 - o1);
        }
        ob[t * 4 + 0] = o0; ob[t * 4 + 1] = o1; ob[t * 4 + 2] = o2; ob[t * 4 + 3] = o3;
        ar[t] = aa;
    }
    __syncthreads();

    int kc = 0;
    for (int i = 0; i < K; ++i) {
        __syncthreads();
        if (!keep[i]) continue;          // uniform: all threads read same LDS value
        ++kc;
        if (kc >= DET) break;            // boxes after 300th kept can't affect output
        double bi0 = ob[i * 4 + 0], bi1 = ob[i * 4 + 1];
        double bi2 = ob[i * 4 + 2], bi3 = ob[i * 4 + 3];
        double ai = ar[i];
        for (int j = i + 1 + tid; j < K; j += 256) {
            if (!keep[j]) continue;
            double w = fmin(bi2, ob[j * 4 + 2]) - fmax(bi0, ob[j * 4 + 0]);
            double h = fmin(bi3, ob[j * 4 + 3]) - fmax(bi1, ob[j * 4 + 1]);
            w = fmax(w, 0.0); h = fmax(h, 0.0);
            double inter = w * h;
            double denom = ai + ar[j] - inter + 1e-7;
            if (inter / denom > 0.45) keep[j] = 0;
        }
    }
    __syncthreads();

    if (tid == 0) {
        float* bo = out + (size_t)img * DET * 4;
        float* so_ = out + (size_t)B * DET * 4 + (size_t)img * DET;
        float* lo = out + (size_t)B * DET * 5 + (size_t)img * DET;
        int o = 0;
        for (int i = 0; i < K && o < DET; ++i) {
            if (!keep[i]) continue;
            bo[o * 4 + 0] = (float)cb[i * 4 + 0];
            bo[o * 4 + 1] = (float)cb[i * 4 + 1];
            bo[o * 4 + 2] = (float)cb[i * 4 + 2];
            bo[o * 4 + 3] = (float)cb[i * 4 + 3];
            so_[o] = (float)__longlong_as_double((long long)sbi[i]);
            lo[o] = (float)(sii[i] % NCLS);
            ++o;
        }
        for (; o < DET; ++o) {
            bo[o * 4 + 0] = 0.f; bo[o * 4 + 1] = 0.f;
            bo[o * 4 + 2] = 0.f; bo[o * 4 + 3] = 0.f;
            so_[o] = -1.0f; lo[o] = -1.0f;
        }
    }
}

extern "C" void kernel_launch(void* const* d_in, const int* in_sizes, int n_in,
                              void* d_out, int out_size, void* d_ws, size_t ws_size,
                              hipStream_t stream) {
    const float* head = (const float*)d_in[0];   // [16,25200,85]
    const float* grid = (const float*)d_in[1];   // [25200,2]
    const float* ag   = (const float*)d_in[2];   // [25200,2]
    const float* stv  = (const float*)d_in[3];   // [25200,1]
    float* out = (float*)d_out;                  // 16*300*4 + 16*300 + 16*300 floats
    char* ws = (char*)d_ws;

    int*    hist = (int*)(ws + 0);               //  16*2048*4 = 131072
    u32*    cnt  = (u32*)(ws + 131072);          //  64
    u64*    cut  = (u64*)(ws + 131200);          //  128
    u64*    sb   = (u64*)(ws + 131328);          //  16*8192*8 = 1048576
    u32*    si   = (u32*)(ws + 1179904);         //  16*8192*4 = 524288
    double* cbox = (double*)(ws + 1704192);      //  16*2048*4*8 = 1048576
    double* obox = (double*)(ws + 2752768);      //  1048576
    double* area = (double*)(ws + 3801344);      //  16*2048*8 = 262144  (end ~4.06 MB)

    hipMemsetAsync(ws, 0, 131136, stream);       // zero hist + cnt each call

    int total = B * NA;
    int blk = (total + 255) / 256;
    k_hist   <<<blk, 256, 0, stream>>>(head, hist);
    k_cut    <<<1,   64,  0, stream>>>(hist, cut);
    k_collect<<<blk, 256, 0, stream>>>(head, cut, cnt, sb, si);
    k_sort   <<<B,   256, 0, stream>>>(cnt, sb, si);
    k_nms    <<<B,   256, 0, stream>>>(head, grid, ag, stv, sb, si, cbox, obox, area, out);
}

// Round 2
// 1269.971 us; speedup vs baseline: 2.1285x; 2.1285x over previous
//
#include <hip/hip_runtime.h>
#include <hip/hip_bf16.h>

#define B    16
#define NA   25200
#define NCH  85
#define NCLS 80
#define K    2048
#define CAP  8192
#define DET  300
#define SPI  (NA * NCLS)               // scores per image = 2,016,000
#define SBASE  0x3FD0000000000000ULL   // bits of 0.25 (double)
#define SSHIFT 42                      // (1.0-0.25) bit-range 2^53 -> 2048 bins

typedef unsigned long long u64;
typedef unsigned int u32;

__device__ __forceinline__ double dsig(float x) {
    return 1.0 / (1.0 + exp(-(double)x));
}
__device__ __forceinline__ float fsig(float x) {
    return 1.0f / (1.0f + __expf(-x));
}

// ---- Pass 1: per-image histogram of f64 score bits (score > 0.25 only).
// Flat (anchor,class) iteration: consecutive lanes read consecutive 4B -> coalesced.
// LDS histogram per block, one global atomic per bin per block.
__global__ void __launch_bounds__(256) k_hist(const float* __restrict__ head, int* __restrict__ hist) {
    __shared__ int h[2048];
    for (int i = threadIdx.x; i < 2048; i += 256) h[i] = 0;
    __syncthreads();
    int img = blockIdx.y;
    const float* base = head + (size_t)img * NA * NCH;
    int stride = gridDim.x * 256;
    for (int s = blockIdx.x * 256 + threadIdx.x; s < SPI; s += stride) {
        int a = (int)((u32)s / NCLS);
        int c = s - a * NCLS;
        float o  = base[a * NCH + 4];
        float cl = base[a * NCH + 5 + c];
        double sc = dsig(o) * dsig(cl);
        if (sc > 0.25) {
            u64 bits = (u64)__double_as_longlong(sc);
            atomicAdd(&h[(int)((bits - SBASE) >> SSHIFT)], 1);
        }
    }
    __syncthreads();
    for (int i = threadIdx.x; i < 2048; i += 256) {
        int v = h[i];
        if (v) atomicAdd(&hist[img * 2048 + i], v);
    }
}

// ---- Pass 2: find cut bin so that >=2048 candidates survive ----
__global__ void k_cut(const int* __restrict__ hist, u64* __restrict__ cut) {
    int img = threadIdx.x;
    if (img >= B) return;
    const int* h = hist + img * 2048;
    int cum = 0; u64 cb = 0;   // cb==0 => take everything >0.25
    for (int b = 2047; b >= 0; --b) {
        cum += h[b];
        if (cum >= K) { cb = SBASE + ((u64)b << SSHIFT); break; }
    }
    cut[img] = cb;
}

// ---- Pass 3: collect candidates at/above the cut (coalesced; f32 wave prefilter) ----
__global__ void __launch_bounds__(256) k_collect(const float* __restrict__ head, const u64* __restrict__ cut,
                          u32* __restrict__ cnt, u64* __restrict__ sb, u32* __restrict__ si) {
    int img = blockIdx.y;
    const float* base = head + (size_t)img * NA * NCH;
    u64 cutb = cut[img];
    // f32 prefilter threshold with 1e-3 relative margin (f32 sigmoid err ~1e-5)
    float pre = 0.2489f;
    if (cutb) {
        float cf = (float)__longlong_as_double((long long)cutb) * 0.999f;
        pre = fmaxf(pre, cf);
    }
    u64* sbi = sb + (size_t)img * CAP;
    u32* sii = si + (size_t)img * CAP;
    int stride = gridDim.x * 256;
    for (int s = blockIdx.x * 256 + threadIdx.x; s < SPI; s += stride) {
        int a = (int)((u32)s / NCLS);
        int c = s - a * NCLS;
        float o  = base[a * NCH + 4];
        float cl = base[a * NCH + 5 + c];
        float s32 = fsig(o) * fsig(cl);
        if (s32 < pre) continue;               // whole-wave skip ~91% of the time
        double sc = dsig(o) * dsig(cl);        // exact f64, identical to k_hist
        if (sc > 0.25) {
            u64 bits = (u64)__double_as_longlong(sc);
            if (bits >= cutb) {
                u32 pos = atomicAdd(&cnt[img], 1u);
                if (pos < CAP) { sbi[pos] = bits; sii[pos] = (u32)(a * NCLS + c); }
            }
        }
    }
}

// ---- Pass 4: per-image exact bitonic sort (desc score-bits, asc index) ----
// LDS fast path for n<=4096 (typical: cnt ~2-4K); global fallback for n=8192.
__global__ void __launch_bounds__(256) k_sort(const u32* __restrict__ cntArr, u64* __restrict__ sb, u32* __restrict__ si) {
    __shared__ u64 SA[4096];
    __shared__ u32 SI[4096];
    int img = blockIdx.x;
    int tid = threadIdx.x;
    u64* A = sb + (size_t)img * CAP;
    u32* I = si + (size_t)img * CAP;
    int cnt = (int)cntArr[img]; if (cnt > CAP) cnt = CAP;
    int n = K; while (n < cnt) n <<= 1;

    if (n <= 4096) {
        for (int i = tid; i < n; i += 256) {
            SA[i] = (i < cnt) ? A[i] : 0ULL;
            SI[i] = (i < cnt) ? I[i] : 0xFFFFFFFFu;
        }
        __syncthreads();
        for (unsigned k = 2; k <= (unsigned)n; k <<= 1) {
            for (unsigned j = k >> 1; j > 0; j >>= 1) {
                for (unsigned i = tid; i < (unsigned)n; i += 256) {
                    unsigned l = i ^ j;
                    if (l > i) {
                        u64 s1 = SA[i], s2 = SA[l];
                        u32 i1 = SI[i], i2 = SI[l];
                        bool before = (s1 > s2) || (s1 == s2 && i1 < i2);
                        bool up = ((i & k) == 0);
                        if (up != before) { SA[i] = s2; SA[l] = s1; SI[i] = i2; SI[l] = i1; }
                    }
                }
                __syncthreads();
            }
        }
        for (int i = tid; i < K; i += 256) { A[i] = SA[i]; I[i] = SI[i]; }
    } else {
        for (int t = cnt + tid; t < n; t += 256) { A[t] = 0ULL; I[t] = 0xFFFFFFFFu; }
        for (unsigned k = 2; k <= (unsigned)n; k <<= 1) {
            for (unsigned j = k >> 1; j > 0; j >>= 1) {
                __syncthreads();
                for (unsigned i = tid; i < (unsigned)n; i += 256) {
                    unsigned l = i ^ j;
                    if (l > i) {
                        u64 s1 = A[i], s2 = A[l];
                        u32 i1 = I[i], i2 = I[l];
                        bool before = (s1 > s2) || (s1 == s2 && i1 < i2);
                        bool up = ((i & k) == 0);
                        if (up != before) { A[i] = s2; A[l] = s1; I[i] = i2; I[l] = i1; }
                    }
                }
            }
        }
    }
}

// ---- Pass 5: decode boxes (f64), class-offset, greedy NMS, emit top-300 ----
__global__ void __launch_bounds__(256) k_nms(const float* __restrict__ head,
        const float* __restrict__ grid, const float* __restrict__ ag, const float* __restrict__ stv,
        const u64* __restrict__ sb, const u32* __restrict__ si,
        double* __restrict__ cbox, double* __restrict__ obox, double* __restrict__ area,
        float* __restrict__ out) {
    int img = blockIdx.x;
    int tid = threadIdx.x;
    const u64* sbi = sb + (size_t)img * CAP;
    const u32* sii = si + (size_t)img * CAP;
    double* cb = cbox + (size_t)img * K * 4;
    double* ob = obox + (size_t)img * K * 4;
    double* ar = area + (size_t)img * K;
    __shared__ char keep[K];
    __shared__ double red[256];

    double lmax = -1e300;
    for (int t = tid; t < K; t += 256) {
        u64 s = sbi[t];
        bool valid = (s != 0ULL);
        keep[t] = valid ? 1 : 0;
        double b0 = 0, b1 = 0, b2 = 0, b3 = 0;
        if (valid) {
            int a = (int)(sii[t] / NCLS);
            const float* row = head + ((size_t)img * NA + a) * NCH;
            double p0 = dsig(row[0]), p1 = dsig(row[1]), p2 = dsig(row[2]), p3 = dsig(row[3]);
            double st = (double)stv[a];
            double xc = (p0 * 2.0 - 0.5 + (double)grid[a * 2 + 0]) * st;
            double yc = (p1 * 2.0 - 0.5 + (double)grid[a * 2 + 1]) * st;
            double w = p2 * 2.0; w = (w * w) * (double)ag[a * 2 + 0];
            double h = p3 * 2.0; h = (h * h) * (double)ag[a * 2 + 1];
            b0 = xc - w * 0.5; b1 = yc - h * 0.5;
            b2 = xc + w * 0.5; b3 = yc + h * 0.5;
            lmax = fmax(lmax, fmax(fmax(b0, b1), fmax(b2, b3)));
        }
        cb[t * 4 + 0] = b0; cb[t * 4 + 1] = b1; cb[t * 4 + 2] = b2; cb[t * 4 + 3] = b3;
    }
    red[tid] = lmax;
    __syncthreads();
    for (int sft = 128; sft > 0; sft >>= 1) {
        if (tid < sft) red[tid] = fmax(red[tid], red[tid + sft]);
        __syncthreads();
    }
    double offb = red[0] + 1.0;   // (max(cand) + 1)

    for (int t = tid; t < K; t += 256) {
        double o0 = 0, o1 = 0, o2 = 0, o3 = 0, aa = 0;
        if (keep[t]) {
            int lab = (int)(sii[t] % NCLS);
            double off = offb * (double)lab;
            o0 = cb[t * 4 + 0] + off; o1 = cb[t * 4 + 1] + off;
            o2 = cb[t * 4 + 2] + off; o3 = cb[t * 4 + 3] + off;
            aa = (o2 - o0) * (o3 - o1);
        }
        ob[t * 4 + 0] = o0; ob[t * 4 + 1] = o1; ob[t * 4 + 2] = o2; ob[t * 4 + 3] = o3;
        ar[t] = aa;
    }
    __syncthreads();

    int kc = 0;
    for (int i = 0; i < K; ++i) {
        __syncthreads();
        if (!keep[i]) continue;          // uniform: all threads read same LDS value
        ++kc;
        if (kc >= DET) break;            // boxes after 300th kept can't affect output
        double bi0 = ob[i * 4 + 0], bi1 = ob[i * 4 + 1];
        double bi2 = ob[i * 4 + 2], bi3 = ob[i * 4 + 3];
        double ai = ar[i];
        for (int j = i + 1 + tid; j < K; j += 256) {
            if (!keep[j]) continue;
            double w = fmin(bi2, ob[j * 4 + 2]) - fmax(bi0, ob[j * 4 + 0]);
            double h = fmin(bi3, ob[j * 4 + 3]) - fmax(bi1, ob[j * 4 + 1]);
            w = fmax(w, 0.0); h = fmax(h, 0.0);
            double inter = w * h;
            double denom = ai + ar[j] - inter + 1e-7;
            if (inter / denom > 0.45) keep[j] = 0;
        }
    }
    __syncthreads();

    if (tid == 0) {
        float* bo = out + (size_t)img * DET * 4;
        float* so_ = out + (size_t)B * DET * 4 + (size_t)img * DET;
        float* lo = out + (size_t)B * DET * 5 + (size_t)img * DET;
        int o = 0;
        for (int i = 0; i < K && o < DET; ++i) {
            if (!keep[i]) continue;
            bo[o * 4 + 0] = (float)cb[i * 4 + 0];
            bo[o * 4 + 1] = (float)cb[i * 4 + 1];
            bo[o * 4 + 2] = (float)cb[i * 4 + 2];
            bo[o * 4 + 3] = (float)cb[i * 4 + 3];
            so_[o] = (float)__longlong_as_double((long long)sbi[i]);
            lo[o] = (float)(sii[i] % NCLS);
            ++o;
        }
        for (; o < DET; ++o) {
            bo[o * 4 + 0] = 0.f; bo[o * 4 + 1] = 0.f;
            bo[o * 4 + 2] = 0.f; bo[o * 4 + 3] = 0.f;
            so_[o] = -1.0f; lo[o] = -1.0f;
        }
    }
}

extern "C" void kernel_launch(void* const* d_in, const int* in_sizes, int n_in,
                              void* d_out, int out_size, void* d_ws, size_t ws_size,
                              hipStream_t stream) {
    const float* head = (const float*)d_in[0];   // [16,25200,85]
    const float* grid = (const float*)d_in[1];   // [25200,2]
    const float* ag   = (const float*)d_in[2];   // [25200,2]
    const float* stv  = (const float*)d_in[3];   // [25200,1]
    float* out = (float*)d_out;                  // 16*300*4 + 16*300 + 16*300 floats
    char* ws = (char*)d_ws;

    int*    hist = (int*)(ws + 0);               //  16*2048*4 = 131072
    u32*    cnt  = (u32*)(ws + 131072);          //  64
    u64*    cut  = (u64*)(ws + 131200);          //  128
    u64*    sb   = (u64*)(ws + 131328);          //  16*8192*8 = 1048576
    u32*    si   = (u32*)(ws + 1179904);         //  16*8192*4 = 524288
    double* cbox = (double*)(ws + 1704192);      //  16*2048*4*8 = 1048576
    double* obox = (double*)(ws + 2752768);      //  1048576
    double* area = (double*)(ws + 3801344);      //  16*2048*8 = 262144  (end ~4.06 MB)

    hipMemsetAsync(ws, 0, 131136, stream);       // zero hist + cnt each call

    dim3 g(64, B);
    k_hist   <<<g, 256, 0, stream>>>(head, hist);
    k_cut    <<<1, 64,  0, stream>>>(hist, cut);
    k_collect<<<g, 256, 0, stream>>>(head, cut, cnt, sb, si);
    k_sort   <<<B, 256, 0, stream>>>(cnt, sb, si);
    k_nms    <<<B, 256, 0, stream>>>(head, grid, ag, stv, sb, si, cbox, obox, area, out);
}

// Round 3
// 715.119 us; speedup vs baseline: 3.7800x; 1.7759x over previous
//
#include <hip/hip_runtime.h>
#include <hip/hip_bf16.h>

#define B    16
#define NA   25200
#define NCH  85
#define NCLS 80
#define K    2048
#define CAP  8192
#define DET  300
#define SPI  (NA * NCLS)               // scores per image = 2,016,000
#define SBASE  0x3FD0000000000000ULL   // bits of 0.25 (double)
#define SSHIFT 42                      // (1.0-0.25) bit-range 2^53 -> 2048 bins

typedef unsigned long long u64;
typedef unsigned int u32;

__device__ __forceinline__ double dsig(float x) {
    return 1.0 / (1.0 + exp(-(double)x));   // np-exact path (decisions only)
}
__device__ __forceinline__ float fsig(float x) {
    return 1.0f / (1.0f + __expf(-x));      // fast screening path
}

// ---- Pass 1: APPROXIMATE f32 histogram of score bins (cut selection only).
// Exactness is restored by k_cut's one-bin margin + k_collect's exact f64 compare.
__global__ void __launch_bounds__(256) k_hist(const float* __restrict__ head, int* __restrict__ hist) {
    __shared__ int h[2048];
    for (int i = threadIdx.x; i < 2048; i += 256) h[i] = 0;
    __syncthreads();
    int img = blockIdx.y;
    const float* base = head + (size_t)img * NA * NCH;
    int stride = gridDim.x * 256;
    for (int s = blockIdx.x * 256 + threadIdx.x; s < SPI; s += stride) {
        int a = (int)((u32)s / NCLS);
        int c = s - a * NCLS;
        float sc = fsig(base[a * NCH + 4]) * fsig(base[a * NCH + 5 + c]);
        if (sc > 0.25f) {
            u64 bits = (u64)__double_as_longlong((double)sc);
            int b = (int)((bits - SBASE) >> SSHIFT);
            b = b > 2047 ? 2047 : b;
            atomicAdd(&h[b], 1);
        }
    }
    __syncthreads();
    for (int i = threadIdx.x; i < 2048; i += 256) {
        int v = h[i];
        if (v) atomicAdd(&hist[img * 2048 + i], v);
    }
}

// ---- Pass 2: cut bin with one-bin safety margin (covers f32 binning error) ----
__global__ void k_cut(const int* __restrict__ hist, u64* __restrict__ cut) {
    int img = threadIdx.x;
    if (img >= B) return;
    const int* h = hist + img * 2048;
    int cum = 0; u64 cb = 0;   // cb==0 => take everything >0.25
    for (int b = 2047; b >= 0; --b) {
        cum += h[b];
        if (cum >= K) { cb = (b >= 1) ? (SBASE + ((u64)(b - 1) << SSHIFT)) : 0ULL; break; }
    }
    cut[img] = cb;
}

// ---- Pass 3: collect candidates with exact-f64 score >= cut (f32 wave prefilter) ----
__global__ void __launch_bounds__(256) k_collect(const float* __restrict__ head, const u64* __restrict__ cut,
                          u32* __restrict__ cnt, u64* __restrict__ sb, u32* __restrict__ si) {
    int img = blockIdx.y;
    const float* base = head + (size_t)img * NA * NCH;
    u64 cutb = cut[img];
    float pre = 0.2489f;
    if (cutb) {
        float cf = (float)__longlong_as_double((long long)cutb) * 0.999f;
        pre = fmaxf(pre, cf);
    }
    u64* sbi = sb + (size_t)img * CAP;
    u32* sii = si + (size_t)img * CAP;
    int stride = gridDim.x * 256;
    for (int s = blockIdx.x * 256 + threadIdx.x; s < SPI; s += stride) {
        int a = (int)((u32)s / NCLS);
        int c = s - a * NCLS;
        float o  = base[a * NCH + 4];
        float cl = base[a * NCH + 5 + c];
        float s32 = fsig(o) * fsig(cl);
        if (s32 < pre) continue;               // skips ~99.7% (f64 exp is rare now)
        double sc = dsig(o) * dsig(cl);        // exact f64 decision
        if (sc > 0.25) {
            u64 bits = (u64)__double_as_longlong(sc);
            if (bits >= cutb) {
                u32 pos = atomicAdd(&cnt[img], 1u);
                if (pos < CAP) { sbi[pos] = bits; sii[pos] = (u32)(a * NCLS + c); }
            }
        }
    }
}

// ---- Pass 4: per-image exact bitonic sort (desc score-bits, asc index) ----
__global__ void __launch_bounds__(512) k_sort(const u32* __restrict__ cntArr, u64* __restrict__ sb, u32* __restrict__ si) {
    __shared__ u64 SA[4096];
    __shared__ u32 SI[4096];
    int img = blockIdx.x;
    int tid = threadIdx.x;
    u64* A = sb + (size_t)img * CAP;
    u32* I = si + (size_t)img * CAP;
    int cnt = (int)cntArr[img]; if (cnt > CAP) cnt = CAP;
    int n = K; while (n < cnt) n <<= 1;

    if (n <= 4096) {
        for (int i = tid; i < n; i += 512) {
            SA[i] = (i < cnt) ? A[i] : 0ULL;
            SI[i] = (i < cnt) ? I[i] : 0xFFFFFFFFu;
        }
        __syncthreads();
        for (unsigned k = 2; k <= (unsigned)n; k <<= 1) {
            for (unsigned j = k >> 1; j > 0; j >>= 1) {
                for (unsigned i = tid; i < (unsigned)n; i += 512) {
                    unsigned l = i ^ j;
                    if (l > i) {
                        u64 s1 = SA[i], s2 = SA[l];
                        u32 i1 = SI[i], i2 = SI[l];
                        bool before = (s1 > s2) || (s1 == s2 && i1 < i2);
                        bool up = ((i & k) == 0);
                        if (up != before) { SA[i] = s2; SA[l] = s1; SI[i] = i2; SI[l] = i1; }
                    }
                }
                __syncthreads();
            }
        }
        for (int i = tid; i < K; i += 512) { A[i] = SA[i]; I[i] = SI[i]; }
    } else {
        for (int t = cnt + tid; t < n; t += 512) { A[t] = 0ULL; I[t] = 0xFFFFFFFFu; }
        for (unsigned k = 2; k <= (unsigned)n; k <<= 1) {
            for (unsigned j = k >> 1; j > 0; j >>= 1) {
                __syncthreads();
                for (unsigned i = tid; i < (unsigned)n; i += 512) {
                    unsigned l = i ^ j;
                    if (l > i) {
                        u64 s1 = A[i], s2 = A[l];
                        u32 i1 = I[i], i2 = I[l];
                        bool before = (s1 > s2) || (s1 == s2 && i1 < i2);
                        bool up = ((i & k) == 0);
                        if (up != before) { A[i] = s2; A[l] = s1; I[i] = i2; I[l] = i1; }
                    }
                }
            }
        }
    }
}

// ---- Pass 5: decode (f64), offset, greedy NMS with register-resident j-boxes,
//      parallel prefix-scan emit. One 1024-thread block per image. ----
__global__ void __launch_bounds__(1024) k_nms(const float* __restrict__ head,
        const float* __restrict__ grid, const float* __restrict__ ag, const float* __restrict__ stv,
        const u64* __restrict__ sb, const u32* __restrict__ si,
        double* __restrict__ obox, double* __restrict__ area,
        float* __restrict__ out) {
    int img = blockIdx.x;
    int tid = threadIdx.x;
    const u64* sbi = sb + (size_t)img * CAP;
    const u32* sii = si + (size_t)img * CAP;
    double* ob = obox + (size_t)img * K * 4;
    double* ar = area + (size_t)img * K;
    __shared__ char keep[K];
    __shared__ int  sc[K];
    __shared__ double red[1024];

    // Phase A1: decode 2 boxes/thread (unoffset, exact f64), track global max
    double bx0[4], bx1[4];
    int lab0 = 0, lab1 = 0;
    bool val0, val1;
    double lmax = -1e300;
    {
        u64 s0 = sbi[tid], s1 = sbi[tid + 1024];
        val0 = (s0 != 0ULL); val1 = (s1 != 0ULL);
        keep[tid] = val0 ? 1 : 0; keep[tid + 1024] = val1 ? 1 : 0;
        #pragma unroll
        for (int q = 0; q < 2; ++q) {
            int t = tid + q * 1024;
            bool v = q ? val1 : val0;
            double* bq = q ? bx1 : bx0;
            bq[0] = bq[1] = bq[2] = bq[3] = 0.0;
            if (v) {
                u32 fi = sii[t];
                int a = (int)(fi / NCLS);
                int lb = (int)(fi % NCLS);
                if (q) lab1 = lb; else lab0 = lb;
                const float* row = head + ((size_t)img * NA + a) * NCH;
                double p0 = dsig(row[0]), p1 = dsig(row[1]), p2 = dsig(row[2]), p3 = dsig(row[3]);
                double st = (double)stv[a];
                double xc = (p0 * 2.0 - 0.5 + (double)grid[a * 2 + 0]) * st;
                double yc = (p1 * 2.0 - 0.5 + (double)grid[a * 2 + 1]) * st;
                double w = p2 * 2.0; w = (w * w) * (double)ag[a * 2 + 0];
                double h = p3 * 2.0; h = (h * h) * (double)ag[a * 2 + 1];
                bq[0] = xc - w * 0.5; bq[1] = yc - h * 0.5;
                bq[2] = xc + w * 0.5; bq[3] = yc + h * 0.5;
                lmax = fmax(lmax, fmax(fmax(bq[0], bq[1]), fmax(bq[2], bq[3])));
            }
        }
    }
    red[tid] = lmax;
    __syncthreads();
    for (int s = 512; s > 0; s >>= 1) {
        if (tid < s) red[tid] = fmax(red[tid], red[tid + s]);
        __syncthreads();
    }
    double offb = red[0] + 1.0;   // (max(cand) + 1), np-exact

    // Phase A2: offset boxes + areas -> registers (j side) + global (i broadcast)
    double oB0[4], oB1[4], aR0, aR1;
    {
        double off0 = offb * (double)lab0;
        oB0[0] = bx0[0] + off0; oB0[1] = bx0[1] + off0;
        oB0[2] = bx0[2] + off0; oB0[3] = bx0[3] + off0;
        aR0 = (oB0[2] - oB0[0]) * (oB0[3] - oB0[1]);
        double off1 = offb * (double)lab1;
        oB1[0] = bx1[0] + off1; oB1[1] = bx1[1] + off1;
        oB1[2] = bx1[2] + off1; oB1[3] = bx1[3] + off1;
        aR1 = (oB1[2] - oB1[0]) * (oB1[3] - oB1[1]);
        ob[tid * 4 + 0] = oB0[0]; ob[tid * 4 + 1] = oB0[1];
        ob[tid * 4 + 2] = oB0[2]; ob[tid * 4 + 3] = oB0[3];
        ar[tid] = aR0;
        ob[(tid + 1024) * 4 + 0] = oB1[0]; ob[(tid + 1024) * 4 + 1] = oB1[1];
        ob[(tid + 1024) * 4 + 2] = oB1[2]; ob[(tid + 1024) * 4 + 3] = oB1[3];
        ar[tid + 1024] = aR1;
    }
    bool alive0 = val0, alive1 = val1;
    __syncthreads();

    // Greedy NMS: ~300 kept => ~300 iterations; j boxes live in registers.
    int kc = 0;
    for (int i = 0; i < K; ++i) {
        __syncthreads();
        if (!keep[i]) continue;           // uniform LDS broadcast
        ++kc;
        if (kc >= DET) break;             // later keeps can't affect first 300
        double bi0 = ob[i * 4 + 0], bi1 = ob[i * 4 + 1];
        double bi2 = ob[i * 4 + 2], bi3 = ob[i * 4 + 3];
        double ai = ar[i];
        // j = tid (branchless compute, predicated clear)
        {
            double w = fmax(fmin(bi2, oB0[2]) - fmax(bi0, oB0[0]), 0.0);
            double h = fmax(fmin(bi3, oB0[3]) - fmax(bi1, oB0[1]), 0.0);
            double inter = w * h;
            double iou = inter / (ai + aR0 - inter + 1e-7);
            if (alive0 && tid > i && iou > 0.45) { alive0 = false; keep[tid] = 0; }
        }
        // j = tid + 1024
        {
            double w = fmax(fmin(bi2, oB1[2]) - fmax(bi0, oB1[0]), 0.0);
            double h = fmax(fmin(bi3, oB1[3]) - fmax(bi1, oB1[1]), 0.0);
            double inter = w * h;
            double iou = inter / (ai + aR1 - inter + 1e-7);
            if (alive1 && (tid + 1024) > i && iou > 0.45) { alive1 = false; keep[tid + 1024] = 0; }
        }
    }
    __syncthreads();

    // Inclusive prefix scan of keep -> ranks (Hillis-Steele, 2 elems/thread)
    sc[tid] = keep[tid];
    sc[tid + 1024] = keep[tid + 1024];
    __syncthreads();
    for (int off = 1; off < K; off <<= 1) {
        int i0 = tid, i1 = tid + 1024;
        int v0 = (i0 >= off) ? sc[i0 - off] : 0;
        int v1 = (i1 >= off) ? sc[i1 - off] : 0;
        __syncthreads();
        sc[i0] += v0; sc[i1] += v1;
        __syncthreads();
    }
    int total = sc[K - 1];

    float* bo  = out + (size_t)img * DET * 4;
    float* so_ = out + (size_t)B * DET * 4 + (size_t)img * DET;
    float* lo  = out + (size_t)B * DET * 5 + (size_t)img * DET;
    if (keep[tid]) {
        int r = sc[tid] - 1;
        if (r < DET) {
            bo[r * 4 + 0] = (float)bx0[0]; bo[r * 4 + 1] = (float)bx0[1];
            bo[r * 4 + 2] = (float)bx0[2]; bo[r * 4 + 3] = (float)bx0[3];
            so_[r] = (float)__longlong_as_double((long long)sbi[tid]);
            lo[r] = (float)lab0;
        }
    }
    if (keep[tid + 1024]) {
        int r = sc[tid + 1024] - 1;
        if (r < DET) {
            bo[r * 4 + 0] = (float)bx1[0]; bo[r * 4 + 1] = (float)bx1[1];
            bo[r * 4 + 2] = (float)bx1[2]; bo[r * 4 + 3] = (float)bx1[3];
            so_[r] = (float)__longlong_as_double((long long)sbi[tid + 1024]);
            lo[r] = (float)lab1;
        }
    }
    if (tid < DET && tid >= total) {       // padding slots [total, 300)
        bo[tid * 4 + 0] = 0.f; bo[tid * 4 + 1] = 0.f;
        bo[tid * 4 + 2] = 0.f; bo[tid * 4 + 3] = 0.f;
        so_[tid] = -1.0f; lo[tid] = -1.0f;
    }
}

extern "C" void kernel_launch(void* const* d_in, const int* in_sizes, int n_in,
                              void* d_out, int out_size, void* d_ws, size_t ws_size,
                              hipStream_t stream) {
    const float* head = (const float*)d_in[0];   // [16,25200,85]
    const float* grid = (const float*)d_in[1];   // [25200,2]
    const float* ag   = (const float*)d_in[2];   // [25200,2]
    const float* stv  = (const float*)d_in[3];   // [25200,1]
    float* out = (float*)d_out;
    char* ws = (char*)d_ws;

    int*    hist = (int*)(ws + 0);               //  16*2048*4 = 131072
    u32*    cnt  = (u32*)(ws + 131072);          //  64
    u64*    cut  = (u64*)(ws + 131200);          //  128
    u64*    sb   = (u64*)(ws + 131328);          //  16*8192*8 = 1048576
    u32*    si   = (u32*)(ws + 1179904);         //  16*8192*4 = 524288
    double* obox = (double*)(ws + 1704192);      //  16*2048*4*8 = 1048576
    double* area = (double*)(ws + 2752768);      //  16*2048*8 = 262144  (end ~3.0 MB)

    hipMemsetAsync(ws, 0, 131136, stream);       // zero hist + cnt each call

    dim3 g(64, B);
    k_hist   <<<g, 256, 0, stream>>>(head, hist);
    k_cut    <<<1, 64,  0, stream>>>(hist, cut);
    k_collect<<<g, 256, 0, stream>>>(head, cut, cnt, sb, si);
    k_sort   <<<B, 512, 0, stream>>>(cnt, sb, si);
    k_nms    <<<B, 1024, 0, stream>>>(head, grid, ag, stv, sb, si, obox, area, out);
}